// Round 1
// baseline (1072.623 us; speedup 1.0000x reference)
//
#include <hip/hip_runtime.h>
#include <math.h>

// Problem constants (from reference)
#define BATCH 1024
#define DIM   512
#define NCLS  100000
#define SCALE_S 64.0f
#define MARGIN  0.5f
#define EPS_REF 1e-7f

// ---------- helpers ----------
__device__ __forceinline__ unsigned short f2bf(float f) {
    union { float f; unsigned u; } v; v.f = f;
    unsigned r = v.u + 0x7FFFu + ((v.u >> 16) & 1u);   // RNE to bf16
    return (unsigned short)(r >> 16);
}

typedef __attribute__((ext_vector_type(8))) short short8;
typedef __attribute__((ext_vector_type(4))) float floatx4;

// ---------- kernel 0: row-normalize features -> bf16; zero rowsum ----------
// grid = 1024 blocks (one per row), block = 128 threads (each owns 4 elems)
__global__ void k_normalize(const float* __restrict__ features,
                            unsigned short* __restrict__ xnbf,
                            float* __restrict__ scale,
                            float* __restrict__ rowsum) {
    const int b = blockIdx.x;
    const int t = threadIdx.x;
    const int lane = t & 63;
    const int wave = t >> 6;
    __shared__ float red[2];

    const float4 v = *(const float4*)(features + (size_t)b * DIM + t * 4);
    float ss = v.x * v.x + v.y * v.y + v.z * v.z + v.w * v.w;
    #pragma unroll
    for (int m = 32; m >= 1; m >>= 1) ss += __shfl_xor(ss, m);
    if (lane == 0) red[wave] = ss;
    __syncthreads();
    const float tot = red[0] + red[1];
    const float sc = 1.0f / fmaxf(sqrtf(tot), 1e-12f);

    ushort4 p;
    p.x = f2bf(v.x * sc); p.y = f2bf(v.y * sc);
    p.z = f2bf(v.z * sc); p.w = f2bf(v.w * sc);
    *(ushort4*)(xnbf + (size_t)b * DIM + t * 4) = p;

    if (t == 0) { scale[b] = sc; rowsum[b] = 0.0f; }
}

// ---------- kernel 1: true-class logit in fp32 ----------
// grid = 1024 blocks, block = 64 (one wave per row)
__global__ void k_tgt(const float* __restrict__ features,
                      const float* __restrict__ W,
                      const int* __restrict__ y,
                      const float* __restrict__ scale,
                      float* __restrict__ tgt) {
    const int b = blockIdx.x;
    const int lane = threadIdx.x;
    const int yb = y[b];
    const float* fr = features + (size_t)b * DIM + lane * 8;
    const float* wr = W + (size_t)yb * DIM + lane * 8;
    float4 f0 = *(const float4*)(fr);
    float4 f1 = *(const float4*)(fr + 4);
    float4 w0 = *(const float4*)(wr);
    float4 w1 = *(const float4*)(wr + 4);
    float d = f0.x * w0.x + f0.y * w0.y + f0.z * w0.z + f0.w * w0.w
            + f1.x * w1.x + f1.y * w1.y + f1.z * w1.z + f1.w * w1.w;
    #pragma unroll
    for (int m = 32; m >= 1; m >>= 1) d += __shfl_xor(d, m);
    if (lane == 0) tgt[b] = d * scale[b];
}

// ---------- kernel 2: MFMA GEMM + fused exp-sum ----------
// grid = (ceil(N/128)=782, M/128=8), block = 256 (4 waves)
// Tile: 128(M) x 128(N), BK=32, 16x16x32 bf16 MFMA, wave -> 64x64 quadrant.
__global__ __launch_bounds__(256)
void k_gemm_expsum(const float* __restrict__ W,
                   const unsigned short* __restrict__ xnbf,
                   float* __restrict__ rowsum) {
    __shared__ unsigned short As[128 * 32];   // A tile, row-major [128][32] bf16
    __shared__ unsigned short Bs[128 * 32];   // B tile (W rows), row-major [128][32] bf16

    const int tid  = threadIdx.x;
    const int wave = tid >> 6;
    const int lane = tid & 63;
    const int quad = lane >> 4;
    const int l15  = lane & 15;
    const int wm   = wave >> 1;   // 0..1 : which 64-row half of M-tile
    const int wn   = wave & 1;    // 0..1 : which 64-col half of N-tile

    const int n0 = blockIdx.x * 128;
    const int m0 = blockIdx.y * 128;

    floatx4 acc[4][4];
    #pragma unroll
    for (int i = 0; i < 4; ++i)
        #pragma unroll
        for (int j = 0; j < 4; ++j)
            acc[i][j] = (floatx4){0.f, 0.f, 0.f, 0.f};

    for (int k0 = 0; k0 < DIM; k0 += 32) {
        __syncthreads();   // protect LDS before overwrite

        // ---- stage A (bf16, straight copy): 128x32 = 8KB, 16B/chunk, 512 chunks
        #pragma unroll
        for (int i = 0; i < 2; ++i) {
            const int ch = i * 256 + tid;
            const int r  = ch >> 2;
            const int kk = (ch & 3) * 8;
            *(uint4*)(&As[r * 32 + kk]) =
                *(const uint4*)(xnbf + (size_t)(m0 + r) * DIM + k0 + kk);
        }
        // ---- stage B (fp32 -> bf16 convert): 128x32 floats, 4 floats/chunk, 1024 chunks
        #pragma unroll
        for (int i = 0; i < 4; ++i) {
            const int ch = i * 256 + tid;
            const int r  = ch >> 3;
            const int kk = (ch & 7) * 4;
            float4 v = make_float4(0.f, 0.f, 0.f, 0.f);
            if (n0 + r < NCLS)
                v = *(const float4*)(W + (size_t)(n0 + r) * DIM + k0 + kk);
            ushort4 p;
            p.x = f2bf(v.x); p.y = f2bf(v.y); p.z = f2bf(v.z); p.w = f2bf(v.w);
            *(ushort4*)(&Bs[r * 32 + kk]) = p;
        }
        __syncthreads();

        // ---- fragments + MFMA
        short8 a[4], b[4];
        #pragma unroll
        for (int mi = 0; mi < 4; ++mi) {
            const int row = wm * 64 + mi * 16 + l15;
            a[mi] = *(const short8*)(&As[row * 32 + quad * 8]);
        }
        #pragma unroll
        for (int ni = 0; ni < 4; ++ni) {
            const int row = wn * 64 + ni * 16 + l15;
            b[ni] = *(const short8*)(&Bs[row * 32 + quad * 8]);
        }
        #pragma unroll
        for (int mi = 0; mi < 4; ++mi)
            #pragma unroll
            for (int ni = 0; ni < 4; ++ni)
                acc[mi][ni] = __builtin_amdgcn_mfma_f32_16x16x32_bf16(
                    a[mi], b[ni], acc[mi][ni], 0, 0, 0);
    }

    // ---- epilogue: e = exp(S*wf), masked n<NCLS, reduce over wave's 64 cols,
    //      one atomicAdd per (row, wave)
    #pragma unroll
    for (int mi = 0; mi < 4; ++mi) {
        #pragma unroll
        for (int reg = 0; reg < 4; ++reg) {
            float p = 0.f;
            #pragma unroll
            for (int ni = 0; ni < 4; ++ni) {
                const int n = n0 + wn * 64 + ni * 16 + l15;
                if (n < NCLS) p += expf(SCALE_S * acc[mi][ni][reg]);
            }
            p += __shfl_xor(p, 1);
            p += __shfl_xor(p, 2);
            p += __shfl_xor(p, 4);
            p += __shfl_xor(p, 8);
            if (l15 == 0) {
                const int m = m0 + wm * 64 + mi * 16 + quad * 4 + reg;
                atomicAdd(&rowsum[m], p);
            }
        }
    }
}

// ---------- kernel 3: finalize loss ----------
// single block, 256 threads, 4 rows each
__global__ void k_finalize(const float* __restrict__ rowsum,
                           const float* __restrict__ tgt,
                           float* __restrict__ out) {
    const int tid = threadIdx.x;
    const int lane = tid & 63;
    const int wave = tid >> 6;
    __shared__ float red[4];

    float s = 0.f;
    #pragma unroll
    for (int i = 0; i < 4; ++i) {
        const int b = tid + i * 256;
        const float traw = tgt[b];
        const float tc = fminf(fmaxf(traw, -1.0f + EPS_REF), 1.0f - EPS_REF);
        const float num = SCALE_S * cosf(acosf(tc) + MARGIN);
        const float excl = rowsum[b] - expf(SCALE_S * traw);
        const float denom = expf(num) + excl;
        s += num - logf(denom);
    }
    #pragma unroll
    for (int m = 32; m >= 1; m >>= 1) s += __shfl_xor(s, m);
    if (lane == 0) red[wave] = s;
    __syncthreads();
    if (tid == 0)
        out[0] = -(red[0] + red[1] + red[2] + red[3]) / (float)BATCH;
}

extern "C" void kernel_launch(void* const* d_in, const int* in_sizes, int n_in,
                              void* d_out, int out_size, void* d_ws, size_t ws_size,
                              hipStream_t stream) {
    const float* features = (const float*)d_in[0];
    const float* W        = (const float*)d_in[1];
    const int*   y        = (const int*)d_in[2];
    float* out = (float*)d_out;

    char* ws = (char*)d_ws;
    unsigned short* xnbf  = (unsigned short*)ws;                  // 1 MB
    float* scale  = (float*)(ws + 1048576);                       // 4 KB
    float* rowsum = (float*)(ws + 1048576 + 4096);                // 4 KB
    float* tgt    = (float*)(ws + 1048576 + 8192);                // 4 KB

    k_normalize<<<BATCH, 128, 0, stream>>>(features, xnbf, scale, rowsum);
    k_tgt<<<BATCH, 64, 0, stream>>>(features, W, y, scale, tgt);
    k_gemm_expsum<<<dim3((NCLS + 127) / 128, BATCH / 128), 256, 0, stream>>>(W, xnbf, rowsum);
    k_finalize<<<1, 256, 0, stream>>>(rowsum, tgt, out);
}

// Round 3
// 789.040 us; speedup vs baseline: 1.3594x; 1.3594x over previous
//
#include <hip/hip_runtime.h>
#include <math.h>

// Problem constants (from reference)
#define BATCH 1024
#define DIM   512
#define NCLS  100000
#define SCALE_S 64.0f
#define MARGIN  0.5f
#define EPS_REF 1e-7f
#define NBLK 782          // ceil(NCLS/128)
#define MBLK 8            // BATCH/128

typedef __attribute__((ext_vector_type(8))) short short8;
typedef __attribute__((ext_vector_type(4))) float floatx4;

// ---------- helpers ----------
__device__ __forceinline__ unsigned short f2bf(float f) {
    union { float f; unsigned u; } v; v.f = f;
    unsigned r = v.u + 0x7FFFu + ((v.u >> 16) & 1u);   // RNE to bf16
    return (unsigned short)(r >> 16);
}

// 8 fp32 -> 8 bf16 by truncation (RTZ). Each pair is one v_perm_b32:
// (a>>16) | (b & 0xFFFF0000). Bias negligible at this problem's scale
// (loss shift ~5e-3 vs threshold 0.91).
__device__ __forceinline__ short8 pack_rtz(float4 lo, float4 hi) {
    uint4 p;
    p.x = (__float_as_uint(lo.x) >> 16) | (__float_as_uint(lo.y) & 0xFFFF0000u);
    p.y = (__float_as_uint(lo.z) >> 16) | (__float_as_uint(lo.w) & 0xFFFF0000u);
    p.z = (__float_as_uint(hi.x) >> 16) | (__float_as_uint(hi.y) & 0xFFFF0000u);
    p.w = (__float_as_uint(hi.z) >> 16) | (__float_as_uint(hi.w) & 0xFFFF0000u);
    return __builtin_bit_cast(short8, p);
}

// ---------- kernel 0: row-normalize features -> bf16; zero rowsum ----------
__global__ void k_normalize(const float* __restrict__ features,
                            unsigned short* __restrict__ xnbf,
                            float* __restrict__ rowsum) {
    const int b = blockIdx.x;
    const int t = threadIdx.x;
    const int lane = t & 63;
    const int wave = t >> 6;
    __shared__ float red[2];

    const float4 v = *(const float4*)(features + (size_t)b * DIM + t * 4);
    float ss = v.x * v.x + v.y * v.y + v.z * v.z + v.w * v.w;
    #pragma unroll
    for (int m = 32; m >= 1; m >>= 1) ss += __shfl_xor(ss, m);
    if (lane == 0) red[wave] = ss;
    __syncthreads();
    const float tot = red[0] + red[1];
    const float sc = 1.0f / fmaxf(sqrtf(tot), 1e-12f);

    ushort4 p;
    p.x = f2bf(v.x * sc); p.y = f2bf(v.y * sc);
    p.z = f2bf(v.z * sc); p.w = f2bf(v.w * sc);
    *(ushort4*)(xnbf + (size_t)b * DIM + t * 4) = p;

    if (t == 0) rowsum[b] = 0.0f;
}

// ---------- kernel 1: true-class logit in fp32 (self-contained norm) ----------
__global__ void k_tgt(const float* __restrict__ features,
                      const float* __restrict__ W,
                      const int* __restrict__ y,
                      float* __restrict__ tgt) {
    const int b = blockIdx.x;
    const int lane = threadIdx.x;
    const int yb = y[b];
    const float* fr = features + (size_t)b * DIM + lane * 8;
    const float* wr = W + (size_t)yb * DIM + lane * 8;
    float4 f0 = *(const float4*)(fr);
    float4 f1 = *(const float4*)(fr + 4);
    float4 w0 = *(const float4*)(wr);
    float4 w1 = *(const float4*)(wr + 4);
    float d = f0.x * w0.x + f0.y * w0.y + f0.z * w0.z + f0.w * w0.w
            + f1.x * w1.x + f1.y * w1.y + f1.z * w1.z + f1.w * w1.w;
    float ss = f0.x * f0.x + f0.y * f0.y + f0.z * f0.z + f0.w * f0.w
             + f1.x * f1.x + f1.y * f1.y + f1.z * f1.z + f1.w * f1.w;
    #pragma unroll
    for (int m = 32; m >= 1; m >>= 1) { d += __shfl_xor(d, m); ss += __shfl_xor(ss, m); }
    if (lane == 0) tgt[b] = d / fmaxf(sqrtf(ss), 1e-12f);
}

// ---------- kernel 2: LDS-free MFMA GEMM + fused exp-sum ----------
// grid = 6256 blocks (782 n-tiles x 8 m-strips), block = 256 (4 waves).
// No __shared__, no barriers: fragments loaded straight global->VGPR with
// immediate k-offsets (full unroll), W converted fp32->bf16 in-register
// (RTZ, one v_perm per pair). XCD swizzle: each XCD owns a disjoint
// contiguous n-range and iterates m within an n-tile, so W streams HBM
// once and B tiles L2-hit across the 8 m-blocks.
__global__ __launch_bounds__(256)
void k_gemm_expsum(const float* __restrict__ W,
                   const unsigned short* __restrict__ xnbf,
                   float* __restrict__ rowsum) {
    const int tid  = threadIdx.x;
    const int wave = tid >> 6;
    const int lane = tid & 63;
    const int quad = lane >> 4;
    const int l15  = lane & 15;
    const int wm   = wave >> 1;   // 64-row half of M-tile
    const int wn   = wave & 1;    // 64-col half of N-tile

    const int bid = blockIdx.x;
    const int xcd = bid & 7;
    const int j   = bid >> 3;            // 0..781
    const int w   = xcd * NBLK + j;      // bijective 0..6255
    const int n_blk = w >> 3;
    const int m_blk = w & 7;

    const int n0 = n_blk * 128;
    const int m0 = m_blk * 128;

    // Per-fragment base pointers (k enters as immediate offsets only).
    const unsigned short* abase[4];
    #pragma unroll
    for (int mi = 0; mi < 4; ++mi) {
        const int m = m0 + wm * 64 + mi * 16 + l15;
        abase[mi] = xnbf + (size_t)m * DIM + quad * 8;
    }
    const float* bbase[4];
    #pragma unroll
    for (int ni = 0; ni < 4; ++ni) {
        int n = n0 + wn * 64 + ni * 16 + l15;
        if (n > NCLS - 1) n = NCLS - 1;   // clamp OOB rows; masked at epilogue
        bbase[ni] = W + (size_t)n * DIM + quad * 8;
    }

    floatx4 acc[4][4];
    #pragma unroll
    for (int i = 0; i < 4; ++i)
        #pragma unroll
        for (int jj = 0; jj < 4; ++jj)
            acc[i][jj] = (floatx4){0.f, 0.f, 0.f, 0.f};

    #pragma unroll
    for (int kk = 0; kk < DIM / 32; ++kk) {          // 16 steps, k0 = kk*32
        short8 a[4], b[4];
        #pragma unroll
        for (int mi = 0; mi < 4; ++mi)
            a[mi] = *(const short8*)(abase[mi] + kk * 32);
        #pragma unroll
        for (int ni = 0; ni < 4; ++ni) {
            float4 lo = *(const float4*)(bbase[ni] + kk * 32);
            float4 hi = *(const float4*)(bbase[ni] + kk * 32 + 4);
            b[ni] = pack_rtz(lo, hi);
        }
        #pragma unroll
        for (int mi = 0; mi < 4; ++mi)
            #pragma unroll
            for (int ni = 0; ni < 4; ++ni)
                acc[mi][ni] = __builtin_amdgcn_mfma_f32_16x16x32_bf16(
                    a[mi], b[ni], acc[mi][ni], 0, 0, 0);
    }

    // Epilogue: sum exp(S*wf) over this block's 128 cols (mask n>=NCLS),
    // reduce across l15 within quad, one atomicAdd per (row, wave).
    #pragma unroll
    for (int mi = 0; mi < 4; ++mi) {
        #pragma unroll
        for (int reg = 0; reg < 4; ++reg) {
            float p = 0.f;
            #pragma unroll
            for (int ni = 0; ni < 4; ++ni) {
                const int n = n0 + wn * 64 + ni * 16 + l15;
                if (n < NCLS) p += __expf(SCALE_S * acc[mi][ni][reg]);
            }
            p += __shfl_xor(p, 1);
            p += __shfl_xor(p, 2);
            p += __shfl_xor(p, 4);
            p += __shfl_xor(p, 8);
            if (l15 == 0) {
                const int m = m0 + wm * 64 + mi * 16 + quad * 4 + reg;
                atomicAdd(&rowsum[m], p);
            }
        }
    }
}

// ---------- kernel 3: finalize loss ----------
__global__ void k_finalize(const float* __restrict__ rowsum,
                           const float* __restrict__ tgt,
                           float* __restrict__ out) {
    const int tid = threadIdx.x;
    const int lane = tid & 63;
    const int wave = tid >> 6;
    __shared__ float red[4];

    float s = 0.f;
    #pragma unroll
    for (int i = 0; i < 4; ++i) {
        const int b = tid + i * 256;
        const float traw = tgt[b];
        const float tc = fminf(fmaxf(traw, -1.0f + EPS_REF), 1.0f - EPS_REF);
        const float num = SCALE_S * cosf(acosf(tc) + MARGIN);
        const float excl = rowsum[b] - expf(SCALE_S * traw);
        const float denom = expf(num) + excl;
        s += num - logf(denom);
    }
    #pragma unroll
    for (int m = 32; m >= 1; m >>= 1) s += __shfl_xor(s, m);
    if (lane == 0) red[wave] = s;
    __syncthreads();
    if (tid == 0)
        out[0] = -(red[0] + red[1] + red[2] + red[3]) / (float)BATCH;
}

extern "C" void kernel_launch(void* const* d_in, const int* in_sizes, int n_in,
                              void* d_out, int out_size, void* d_ws, size_t ws_size,
                              hipStream_t stream) {
    const float* features = (const float*)d_in[0];
    const float* W        = (const float*)d_in[1];
    const int*   y        = (const int*)d_in[2];
    float* out = (float*)d_out;

    char* ws = (char*)d_ws;
    unsigned short* xnbf  = (unsigned short*)ws;                  // 1 MB
    float* rowsum = (float*)(ws + 1048576);                       // 4 KB
    float* tgt    = (float*)(ws + 1048576 + 4096);                // 4 KB

    k_normalize<<<BATCH, 128, 0, stream>>>(features, xnbf, rowsum);
    k_tgt<<<BATCH, 64, 0, stream>>>(features, W, y, tgt);
    k_gemm_expsum<<<NBLK * MBLK, 256, 0, stream>>>(W, xnbf, rowsum);
    k_finalize<<<1, 256, 0, stream>>>(rowsum, tgt, out);
}

// Round 4
// 473.676 us; speedup vs baseline: 2.2645x; 1.6658x over previous
//
#include <hip/hip_runtime.h>
#include <math.h>

// Problem constants (from reference)
#define BATCH 1024
#define DIM   512
#define NCLS  100000
#define SCALE_S 64.0f
#define MARGIN  0.5f
#define EPS_REF 1e-7f
#define NBLK 782          // ceil(NCLS/128)
#define MBLK 8            // BATCH/128
#define BK   64           // K-slab per barrier iteration

typedef __attribute__((ext_vector_type(8))) short short8;
typedef __attribute__((ext_vector_type(4))) float floatx4;

// ---------- helpers ----------
__device__ __forceinline__ unsigned short f2bf(float f) {
    union { float f; unsigned u; } v; v.f = f;
    unsigned r = v.u + 0x7FFFu + ((v.u >> 16) & 1u);   // RNE to bf16
    return (unsigned short)(r >> 16);
}

// async global->LDS, 16B per lane; LDS dest = wave-uniform base + lane*16
__device__ __forceinline__ void gload_lds16(const void* g, void* l) {
    __builtin_amdgcn_global_load_lds(
        (const __attribute__((address_space(1))) void*)g,
        (__attribute__((address_space(3))) void*)l, 16, 0, 0);
}

// ---------- kernel 0: row-normalize features -> bf16; zero rowsum ----------
__global__ void k_normalize(const float* __restrict__ features,
                            unsigned short* __restrict__ xnbf,
                            float* __restrict__ rowsum) {
    const int b = blockIdx.x;
    const int t = threadIdx.x;
    const int lane = t & 63;
    const int wave = t >> 6;
    __shared__ float red[2];

    const float4 v = *(const float4*)(features + (size_t)b * DIM + t * 4);
    float ss = v.x * v.x + v.y * v.y + v.z * v.z + v.w * v.w;
    #pragma unroll
    for (int m = 32; m >= 1; m >>= 1) ss += __shfl_xor(ss, m);
    if (lane == 0) red[wave] = ss;
    __syncthreads();
    const float tot = red[0] + red[1];
    const float sc = 1.0f / fmaxf(sqrtf(tot), 1e-12f);

    ushort4 p;
    p.x = f2bf(v.x * sc); p.y = f2bf(v.y * sc);
    p.z = f2bf(v.z * sc); p.w = f2bf(v.w * sc);
    *(ushort4*)(xnbf + (size_t)b * DIM + t * 4) = p;

    if (t == 0) rowsum[b] = 0.0f;
}

// ---------- kernel 1: true-class logit in fp32 (self-contained norm) ----------
__global__ void k_tgt(const float* __restrict__ features,
                      const float* __restrict__ W,
                      const int* __restrict__ y,
                      float* __restrict__ tgt) {
    const int b = blockIdx.x;
    const int lane = threadIdx.x;
    const int yb = y[b];
    const float* fr = features + (size_t)b * DIM + lane * 8;
    const float* wr = W + (size_t)yb * DIM + lane * 8;
    float4 f0 = *(const float4*)(fr);
    float4 f1 = *(const float4*)(fr + 4);
    float4 w0 = *(const float4*)(wr);
    float4 w1 = *(const float4*)(wr + 4);
    float d = f0.x * w0.x + f0.y * w0.y + f0.z * w0.z + f0.w * w0.w
            + f1.x * w1.x + f1.y * w1.y + f1.z * w1.z + f1.w * w1.w;
    float ss = f0.x * f0.x + f0.y * f0.y + f0.z * f0.z + f0.w * f0.w
             + f1.x * f1.x + f1.y * f1.y + f1.z * f1.z + f1.w * f1.w;
    #pragma unroll
    for (int m = 32; m >= 1; m >>= 1) { d += __shfl_xor(d, m); ss += __shfl_xor(ss, m); }
    if (lane == 0) tgt[b] = d / fmaxf(sqrtf(ss), 1e-12f);
}

// ---------- kernel 2: LDS-staged MFMA GEMM + fused exp-sum ----------
// 128x128 tile, BK=64, 4 waves. A staged async via global_load_lds (bf16);
// B staged coalesced (wave = 4 rows x 256B) through regs with fp32->bf16
// v_perm pack. LDS layout XOR-swizzled: 16B chunk c of row r lives at
// chunk (c ^ (r&7)) -> conflict-free ds_read_b128/ds_write at bank floor,
// and compatible with global_load_lds's lane*16 dest rule.
__global__ __launch_bounds__(256)
void k_gemm_expsum(const float* __restrict__ W,
                   const unsigned short* __restrict__ xnbf,
                   float* __restrict__ rowsum) {
    __shared__ unsigned short As[128 * BK];   // 16 KB
    __shared__ unsigned short Bs[128 * BK];   // 16 KB

    const int tid  = threadIdx.x;
    const int wave = tid >> 6;
    const int lane = tid & 63;
    const int quad = lane >> 4;
    const int l15  = lane & 15;
    const int wm   = wave >> 1;   // 64-row half of M-tile
    const int wn   = wave & 1;    // 64-col half of N-tile

    // XCD swizzle: each XCD owns a disjoint n-range, iterates m within an
    // n-tile -> W streams HBM once, L2-hits across the 8 m-blocks.
    const int bid = blockIdx.x;
    const int xcd = bid & 7;
    const int j   = bid >> 3;
    const int w   = xcd * NBLK + j;
    const int n_blk = w >> 3;
    const int m_blk = w & 7;
    const int n0 = n_blk * 128;
    const int m0 = m_blk * 128;

    // ---- A staging addresses (global_load_lds): lane = r_local*8 + c_swz
    const int a_rl  = lane >> 3;          // 0..7 row within 8-row group
    const int a_cs  = lane & 7;           // swizzled chunk slot
    // lane's global source chunk = c_swz ^ r_local (so LDS[r][cs] = G[r][cs^r])
    const unsigned short* a_src[4];
    unsigned short* a_dst[4];
    #pragma unroll
    for (int i = 0; i < 4; ++i) {
        const int r = wave * 32 + i * 8 + a_rl;          // tile row
        a_src[i] = xnbf + (size_t)(m0 + r) * DIM + (a_cs ^ a_rl) * 8;
        a_dst[i] = &As[(wave * 32 + i * 8) * BK];        // wave-uniform base
    }

    // ---- B staging addresses: 8 passes, pass p covers rows p*16..p*16+15;
    // wave covers 4 rows x 256B contiguous (fully coalesced).
    const int b_rl = lane >> 4;           // 0..3
    const int b_j  = lane & 15;           // 16B fp32 chunk in row (0..15)
    const float* b_src[8];
    int b_ldso[8];
    #pragma unroll
    for (int p = 0; p < 8; ++p) {
        const int r = p * 16 + wave * 4 + b_rl;
        int n = n0 + r;
        if (n > NCLS - 1) n = NCLS - 1;   // clamp; masked at epilogue
        b_src[p] = W + (size_t)n * DIM + b_j * 4;
        const int c  = b_j >> 1;          // bf16 16B chunk
        const int sub = b_j & 1;          // 8B half of chunk
        b_ldso[p] = r * BK + ((c ^ (r & 7)) * 8) + sub * 4;   // ushort index
    }

    // ---- fragment read offsets (ushort index); kc=1 is offset ^ 32
    const int sA = l15 & 7;
    int aoff[4], boff[4];
    #pragma unroll
    for (int mi = 0; mi < 4; ++mi) {
        const int r = wm * 64 + mi * 16 + l15;
        aoff[mi] = r * BK + (quad ^ sA) * 8;
    }
    #pragma unroll
    for (int ni = 0; ni < 4; ++ni) {
        const int r = wn * 64 + ni * 16 + l15;
        boff[ni] = r * BK + (quad ^ sA) * 8;
    }

    floatx4 acc[4][4];
    #pragma unroll
    for (int i = 0; i < 4; ++i)
        #pragma unroll
        for (int jj = 0; jj < 4; ++jj)
            acc[i][jj] = (floatx4){0.f, 0.f, 0.f, 0.f};

    for (int kt = 0; kt < DIM / BK; ++kt) {       // 8 iterations
        __syncthreads();                          // previous reads done

        // A: 4 async issues per wave (16B/lane, 8 rows per issue)
        #pragma unroll
        for (int i = 0; i < 4; ++i)
            gload_lds16(a_src[i] + kt * BK, a_dst[i]);

        // B: 8 coalesced passes: load float4, pack RTZ, ds_write 8B
        #pragma unroll
        for (int p = 0; p < 8; ++p) {
            const float4 v = *(const float4*)(b_src[p] + kt * BK);
            uint2 pk;
            pk.x = (__float_as_uint(v.x) >> 16) | (__float_as_uint(v.y) & 0xFFFF0000u);
            pk.y = (__float_as_uint(v.z) >> 16) | (__float_as_uint(v.w) & 0xFFFF0000u);
            *(uint2*)(&Bs[b_ldso[p]]) = pk;
        }

        __syncthreads();                          // staging visible

        #pragma unroll
        for (int kc = 0; kc < 2; ++kc) {          // two 32-k MFMA chunks
            short8 a[4], b[4];
            #pragma unroll
            for (int mi = 0; mi < 4; ++mi)
                a[mi] = *(const short8*)(&As[aoff[mi] ^ (kc * 32)]);
            #pragma unroll
            for (int ni = 0; ni < 4; ++ni)
                b[ni] = *(const short8*)(&Bs[boff[ni] ^ (kc * 32)]);
            #pragma unroll
            for (int mi = 0; mi < 4; ++mi)
                #pragma unroll
                for (int ni = 0; ni < 4; ++ni)
                    acc[mi][ni] = __builtin_amdgcn_mfma_f32_16x16x32_bf16(
                        a[mi], b[ni], acc[mi][ni], 0, 0, 0);
        }
    }

    // Epilogue: sum exp(S*wf) over block's cols (mask n>=NCLS), reduce
    // across l15, one atomicAdd per (row, wave).
    #pragma unroll
    for (int mi = 0; mi < 4; ++mi) {
        #pragma unroll
        for (int reg = 0; reg < 4; ++reg) {
            float p = 0.f;
            #pragma unroll
            for (int ni = 0; ni < 4; ++ni) {
                const int n = n0 + wn * 64 + ni * 16 + l15;
                if (n < NCLS) p += __expf(SCALE_S * acc[mi][ni][reg]);
            }
            p += __shfl_xor(p, 1);
            p += __shfl_xor(p, 2);
            p += __shfl_xor(p, 4);
            p += __shfl_xor(p, 8);
            if (l15 == 0) {
                const int m = m0 + wm * 64 + mi * 16 + quad * 4 + reg;
                atomicAdd(&rowsum[m], p);
            }
        }
    }
}

// ---------- kernel 3: finalize loss ----------
__global__ void k_finalize(const float* __restrict__ rowsum,
                           const float* __restrict__ tgt,
                           float* __restrict__ out) {
    const int tid = threadIdx.x;
    const int lane = tid & 63;
    const int wave = tid >> 6;
    __shared__ float red[4];

    float s = 0.f;
    #pragma unroll
    for (int i = 0; i < 4; ++i) {
        const int b = tid + i * 256;
        const float traw = tgt[b];
        const float tc = fminf(fmaxf(traw, -1.0f + EPS_REF), 1.0f - EPS_REF);
        const float num = SCALE_S * cosf(acosf(tc) + MARGIN);
        const float excl = rowsum[b] - expf(SCALE_S * traw);
        const float denom = expf(num) + excl;
        s += num - logf(denom);
    }
    #pragma unroll
    for (int m = 32; m >= 1; m >>= 1) s += __shfl_xor(s, m);
    if (lane == 0) red[wave] = s;
    __syncthreads();
    if (tid == 0)
        out[0] = -(red[0] + red[1] + red[2] + red[3]) / (float)BATCH;
}

extern "C" void kernel_launch(void* const* d_in, const int* in_sizes, int n_in,
                              void* d_out, int out_size, void* d_ws, size_t ws_size,
                              hipStream_t stream) {
    const float* features = (const float*)d_in[0];
    const float* W        = (const float*)d_in[1];
    const int*   y        = (const int*)d_in[2];
    float* out = (float*)d_out;

    char* ws = (char*)d_ws;
    unsigned short* xnbf  = (unsigned short*)ws;                  // 1 MB
    float* rowsum = (float*)(ws + 1048576);                       // 4 KB
    float* tgt    = (float*)(ws + 1048576 + 4096);                // 4 KB

    k_normalize<<<BATCH, 128, 0, stream>>>(features, xnbf, rowsum);
    k_tgt<<<BATCH, 64, 0, stream>>>(features, W, y, tgt);
    k_gemm_expsum<<<NBLK * MBLK, 256, 0, stream>>>(W, xnbf, rowsum);
    k_finalize<<<1, 256, 0, stream>>>(rowsum, tgt, out);
}